// Round 5
// baseline (813.904 us; speedup 1.0000x reference)
//
#include <hip/hip_runtime.h>
#include <math.h>

#define BATCH 4
#define NPTS  8192
#define KNN   16
#define KK    17               // top-17 incl. self (self key: d2 = +0 exactly)
#define NQ    (BATCH*NPTS)     // 32768
#define JMASK 0x1FFFu
#define EMASK 0xFFFFE000u      // top 19 bits of d2 (d2 >= +0 -> uint-sortable)
#define TOTAL_EDGES (BATCH*NPTS*KNN)

// ---- grid geometry: 32^3 cells over [-4.5,4.5]^3, outliers clamped into edge cells
#define GC    32
#define GLO   (-4.5f)
#define GS    (9.0f/32.0f)     // 0.28125
#define GINV  (32.0f/9.0f)
#define NCELL (GC*GC*GC)       // 32768 per batch

#define QPW   16               // queries per wave (block = 1 wave of 64)
#define GRIDQ (NQ/QPW)         // 2048 blocks

__device__ __forceinline__ int cell_coord(float x) {
    int c = (int)floorf((x - GLO) * GINV);
    return min(GC - 1, max(0, c));
}

__device__ __forceinline__ unsigned mkkey(const float4 p, float xi, float yi,
                                          float zi, float sqi, unsigned j) {
    const float dot = fmaf(p.x, xi, fmaf(p.y, yi, p.z * zi));
    const float d2  = fmaf(-2.0f, dot, p.w) + sqi;   // self: exact +0
    return (__float_as_uint(d2) & EMASK) | j;
}

__device__ __forceinline__ void ins17(unsigned (&a)[KK], unsigned key) {
    #pragma unroll
    for (int k = KK - 1; k >= 1; --k) a[k] = min(a[k], max(a[k - 1], key));
    a[0] = min(a[0], key);
}

// K1: per-point cell histogram (global atomics); thread 0 zeroes accumulators
__global__ void pel_hist(const float* __restrict__ pref, unsigned* __restrict__ hist,
                         float* __restrict__ acc, unsigned* __restrict__ bcnt) {
    const int idx = blockIdx.x * 256 + threadIdx.x;      // 0..NQ-1
    if (idx == 0) { acc[0] = 0.0f; bcnt[0] = 0u; }
    const int b = idx >> 13;
    const int cx = cell_coord(pref[3*idx]);
    const int cy = cell_coord(pref[3*idx+1]);
    const int cz = cell_coord(pref[3*idx+2]);
    atomicAdd(&hist[b * NCELL + (cz * GC + cy) * GC + cx], 1u);
}

// K2: per-batch exclusive prefix scan of 32768 cell counts (1 block/batch)
__global__ __launch_bounds__(1024)
void pel_scan(const unsigned* __restrict__ hist, unsigned* __restrict__ off) {
    __shared__ unsigned s[1024];
    const unsigned* h = hist + blockIdx.x * NCELL;
    unsigned*       o = off  + blockIdx.x * NCELL;
    const int t = threadIdx.x;
    unsigned v[32], tot = 0;
    #pragma unroll
    for (int k = 0; k < 32; ++k) { v[k] = h[t * 32 + k]; tot += v[k]; }
    s[t] = tot;
    __syncthreads();
    for (int d = 1; d < 1024; d <<= 1) {          // Hillis-Steele inclusive
        const unsigned add = (t >= d) ? s[t - d] : 0u;
        __syncthreads();
        s[t] += add;
        __syncthreads();
    }
    unsigned run = s[t] - tot;                    // exclusive base
    #pragma unroll
    for (int k = 0; k < 32; ++k) { o[t * 32 + k] = run; run += v[k]; }
}

// K3: scatter points into cell-sorted order, packing (x,y,z,||x||^2) for ref+pred.
// atomicAdd turns off[] from starts into ends -> cell c range = [c?off[c-1]:0, off[c])
__global__ void pel_scatter(const float* __restrict__ pref, const float* __restrict__ pts,
                            unsigned* __restrict__ off,
                            float4* __restrict__ p4r, float4* __restrict__ p4p) {
    const int idx = blockIdx.x * 256 + threadIdx.x;
    const int b = idx >> 13;
    const float x = pref[3*idx], y = pref[3*idx+1], z = pref[3*idx+2];
    const int cid = (cell_coord(z) * GC + cell_coord(y)) * GC + cell_coord(x);
    const unsigned pos = atomicAdd(&off[b * NCELL + cid], 1u);
    p4r[b * NPTS + pos] = make_float4(x, y, z, fmaf(x, x, fmaf(y, y, z*z)));
    const float px = pts[3*idx], py = pts[3*idx+1], pz = pts[3*idx+2];
    p4p[b * NPTS + pos] = make_float4(px, py, pz, fmaf(px, px, fmaf(py, py, pz*pz)));
}

// K4: shell-expanding exact KNN + loss. 1 wave/block; 16 queries x 4 splits.
// Lanes = consecutive sorted positions -> spatially co-located -> low divergence.
__global__ __launch_bounds__(64)
void pel_query(const float4* __restrict__ P4r, const float4* __restrict__ P4p,
               const unsigned* __restrict__ off,
               float* __restrict__ acc_ws, unsigned* __restrict__ bcnt,
               float* __restrict__ out)
{
    __shared__ unsigned s_key[KK][64];
    __shared__ unsigned s_tau[QPW];

    const int t  = threadIdx.x;
    const int lq = t & (QPW - 1);           // query slot 0..15
    const int sp = t >> 4;                  // split 0..3
    const int q  = blockIdx.x * QPW + lq;   // global sorted-query index
    const int b  = q >> 13;
    const int i  = q & (NPTS - 1);          // position within batch arrays

    const float4*   __restrict__ Pq   = P4r + b * NPTS;
    const float4*   __restrict__ Pp   = P4p + b * NPTS;
    const unsigned* __restrict__ offb = off + b * NCELL;

    const float4 self = Pq[i];
    const float xi = self.x, yi = self.y, zi = self.z, sqi = self.w;
    const int cx = cell_coord(xi), cy = cell_coord(yi), cz = cell_coord(zi);

    unsigned a[KK];
    #pragma unroll
    for (int k = 0; k < KK; ++k) a[k] = 0xFFFFFFFFu;

    auto scan_range = [&](int c0, int c1) {   // cells c0..c1 contiguous in x
        const unsigned s0 = (c0 == 0) ? 0u : offb[c0 - 1];
        const unsigned e0 = offb[c1];
        for (unsigned j = s0; j < e0; ++j)
            ins17(a, mkkey(Pq[j], xi, yi, zi, sqi, j));
    };

    bool done = false;
    for (int r = 1; r <= GC; ++r) {
        if (!done) {
            int m = 0;
            for (int dz = -r; dz <= r; ++dz) {
                const int z = cz + dz;
                for (int dy = -r; dy <= r; ++dy, ++m) {
                    if ((m & 3) != sp) continue;         // row->split partition
                    const int y = cy + dy;
                    if ((unsigned)z >= GC || (unsigned)y >= GC) continue;
                    const int rowc = (z * GC + y) * GC;
                    const bool full = (r == 1) | (dz == -r) | (dz == r) |
                                      (dy == -r) | (dy == r);  // row's first shell
                    if (full) {
                        scan_range(rowc + max(0, cx - r), rowc + min(GC - 1, cx + r));
                    } else {                              // interior row: x = cx +- r only
                        if (cx - r >= 0) scan_range(rowc + cx - r, rowc + cx - r);
                        if (cx + r < GC) scan_range(rowc + cx + r, rowc + cx + r);
                    }
                }
            }
        }
        // cheap sound upper bound on union-17th: exact 17th of each split-pair
        // (bitonic max-min identity over sorted 17-lists), then min across pairs
        unsigned tp = 0;
        #pragma unroll
        for (int k = 0; k < KK; ++k) {
            const unsigned bk = (unsigned)__shfl_xor((int)a[KK - 1 - k], 16, 64);
            tp = max(tp, min(a[k], bk));
        }
        const unsigned th = min(tp, (unsigned)__shfl_xor((int)tp, 32, 64));
        // distance from query to the unscanned region (grid-edge faces covered: inf)
        const float fx0 = (cx - r <= 0)      ? 1e30f : xi - (GLO + (float)(cx - r) * GS);
        const float fx1 = (cx + r >= GC - 1) ? 1e30f : (GLO + (float)(cx + r + 1) * GS) - xi;
        const float fy0 = (cy - r <= 0)      ? 1e30f : yi - (GLO + (float)(cy - r) * GS);
        const float fy1 = (cy + r >= GC - 1) ? 1e30f : (GLO + (float)(cy + r + 1) * GS) - yi;
        const float fz0 = (cz - r <= 0)      ? 1e30f : zi - (GLO + (float)(cz - r) * GS);
        const float fz1 = (cz + r >= GC - 1) ? 1e30f : (GLO + (float)(cz + r + 1) * GS) - zi;
        const float mf = fminf(fminf(fminf(fx0, fx1), fminf(fy0, fy1)), fminf(fz0, fz1));
        const float tf = __uint_as_float(th & EMASK);   // NaN while <17 seen -> not done
        done = done || (mf * mf >= tf);
        if (__all(done)) break;
    }

    // exact union-17th via one LDS merge (4 sorted runs per query)
    #pragma unroll
    for (int k = 0; k < KK; ++k) s_key[k][t] = a[k];
    __syncthreads();
    if (t < 32) {
        const int mq = t & (QPW - 1), half = t >> 4;   // 2 runs per lane-half
        unsigned mm[KK];
        #pragma unroll
        for (int k = 0; k < KK; ++k) mm[k] = 0xFFFFFFFFu;
        for (int s2 = 2 * half; s2 < 2 * half + 2; ++s2) {
            const int col = mq + QPW * s2;
            for (int k = 0; k < KK; ++k) {
                const unsigned c = s_key[k][col];
                if (c >= mm[KK - 1]) break;            // runs sorted ascending
                ins17(mm, c);
            }
        }
        unsigned tau = 0;
        #pragma unroll
        for (int k = 0; k < KK; ++k) {
            const unsigned bk = (unsigned)__shfl_xor((int)mm[KK - 1 - k], 16, 64);
            tau = max(tau, min(mm[k], bk));
        }
        if (half == 0) s_tau[mq] = tau;                // exact 17th key
    }
    __syncthreads();
    const unsigned tauK = s_tau[lq];

    // loss over own accepted keys (exactly 17 across the 4 splits; self adds 0)
    const float4 selfp = Pp[i];
    float accv = 0.0f;
    #pragma unroll
    for (int k = 0; k < KK; ++k) {
        if (a[k] <= tauK) {
            const int j = (int)(a[k] & JMASK);
            const float4 pr = Pq[j];
            const float dotr = fmaf(pr.x, xi, fmaf(pr.y, yi, pr.z * zi));
            const float d2r  = fmaxf(fmaf(-2.0f, dotr, pr.w) + sqi, 0.0f);
            const float4 pp = Pp[j];
            const float dotp = fmaf(pp.x, selfp.x, fmaf(pp.y, selfp.y, pp.z * selfp.z));
            const float d2p  = fmaxf(fmaf(-2.0f, dotp, pp.w) + selfp.w, 0.0f);
            accv += fabsf(sqrtf(d2r) - sqrtf(d2p));
        }
    }

    #pragma unroll
    for (int o = 32; o > 0; o >>= 1) accv += __shfl_down(accv, o, 64);
    if (t == 0) {
        atomicAdd(acc_ws, accv);
        __threadfence();
        const unsigned old = atomicAdd(bcnt, 1u);
        if (old == GRIDQ - 1) {
            __threadfence();
            const float total = atomicAdd(acc_ws, 0.0f);
            out[0] = total * (1.0f / (float)TOTAL_EDGES);
        }
    }
}

extern "C" void kernel_launch(void* const* d_in, const int* in_sizes, int n_in,
                              void* d_out, int out_size, void* d_ws, size_t ws_size,
                              hipStream_t stream) {
    const float* pref = (const float*)d_in[0];
    const float* pts  = (const float*)d_in[1];
    // ws layout (1.57 MB): [P4r 512K (aliases hist during build)][P4p 512K][off 512K][acc,bcnt]
    float4*   P4r  = (float4*)d_ws;
    float4*   P4p  = P4r + NQ;
    unsigned* hist = (unsigned*)d_ws;                          // alias: dead after scan
    unsigned* off  = (unsigned*)((char*)d_ws + 1048576);
    float*    acc  = (float*)((char*)d_ws + 1572864);
    unsigned* bcnt = (unsigned*)(acc + 1);
    float*    out  = (float*)d_out;

    hipMemsetAsync(hist, 0, BATCH * NCELL * sizeof(unsigned), stream);
    pel_hist   <<<NQ / 256, 256, 0, stream>>>(pref, hist, acc, bcnt);
    pel_scan   <<<BATCH, 1024, 0, stream>>>(hist, off);
    pel_scatter<<<NQ / 256, 256, 0, stream>>>(pref, pts, off, P4r, P4p);
    pel_query  <<<GRIDQ, 64, 0, stream>>>(P4r, P4p, off, acc, bcnt, out);
}

// Round 6
// 290.925 us; speedup vs baseline: 2.7976x; 2.7976x over previous
//
#include <hip/hip_runtime.h>
#include <math.h>

#define BATCH 4
#define NPTS  8192
#define KNN   16
#define KK    17               // top-17 incl. self (self key: d2 = +0 exactly)
#define QPB   16               // queries per block
#define SPLITS 16              // threads per query
#define BLOCK (QPB*SPLITS)     // 256
#define RANGE (NPTS/SPLITS)    // 512
#define SAMPLE 64              // phase-A sample per thread (union = 1024)
#define AL    8                // phase-A per-thread list size
#define CAP   21               // key-buffer rows (compact at >17; max row 20)
#define CHUNK 4                // loads in flight per thread (16 VGPR)
#define NQ    (BATCH*NPTS)     // 32768
#define GRIDQ (NQ/QPB)         // 2048 blocks x 4 waves = 8192 waves
#define JMASK 0x1FFFu
#define EMASK 0xFFFFE000u      // top 19 bits of d2 (d2 >= +0 -> uint-sortable)
#define TOTAL_EDGES (BATCH*NPTS*KNN)

// pack (-2x,-2y,-2z,||x||^2) for ref AND pred; zero loss accumulator + counter
__global__ void pel_pack(const float* __restrict__ pref, const float* __restrict__ pts,
                         float4* __restrict__ p4r, float4* __restrict__ p4p,
                         float* __restrict__ acc, unsigned* __restrict__ bcnt) {
    const int idx = blockIdx.x * 256 + threadIdx.x;
    if (idx == 0) { acc[0] = 0.0f; bcnt[0] = 0u; }
    if (idx < NQ) {
        float x = pref[3*idx], y = pref[3*idx+1], z = pref[3*idx+2];
        p4r[idx] = make_float4(-2.f*x, -2.f*y, -2.f*z, fmaf(x, x, fmaf(y, y, z*z)));
        x = pts[3*idx]; y = pts[3*idx+1]; z = pts[3*idx+2];
        p4p[idx] = make_float4(-2.f*x, -2.f*y, -2.f*z, fmaf(x, x, fmaf(y, y, z*z)));
    }
}

// p = (-2xj,-2yj,-2zj,sqj); e = sqj - 2 xj.xi  (d2 = e + sqi; self -> +0 exact)
__device__ __forceinline__ unsigned mkkey(const float4 p, float xi, float yi,
                                          float zi, float sqi, unsigned j) {
    const float e  = fmaf(p.x, xi, fmaf(p.y, yi, p.z * zi)) + p.w;
    const float d2 = e + sqi;
    return (__float_as_uint(d2) & EMASK) | j;
}

__device__ __forceinline__ void ins17(unsigned (&a)[KK], unsigned key) {
    #pragma unroll
    for (int k = KK - 1; k >= 1; --k) a[k] = min(a[k], max(a[k - 1], key));
    a[0] = min(a[0], key);
}

// exact 17th of 16 sorted runs (RL entries each): all 64 lanes run; lane L merges
// runs [8h, 8h+8) serially (h=(L>>4)&1), bitonic-combine with partner L^16.
template<int RL>
__device__ __forceinline__ unsigned merge_tau(const unsigned (*s_key)[BLOCK], int t) {
    const int mq = t & (QPB - 1), half = (t >> 4) & 1;
    unsigned m[KK];
    #pragma unroll
    for (int k = 0; k < KK; ++k) m[k] = 0xFFFFFFFFu;
    for (int s = 8 * half; s < 8 * half + 8; ++s) {
        const int col = mq + s * QPB;
        for (int k = 0; k < RL; ++k) {
            const unsigned c = s_key[k][col];
            if (c >= m[KK - 1]) break;            // runs sorted ascending
            ins17(m, c);
        }
    }
    unsigned tau = 0;
    #pragma unroll
    for (int k = 0; k < KK; ++k) {
        const unsigned bk = (unsigned)__shfl_xor((int)m[KK - 1 - k], 16, 64);
        tau = max(tau, min(m[k], bk));
    }
    return tau;   // valid on lanes with (t>>4)&1 == 0 paired with ^16
}

__global__ __launch_bounds__(BLOCK, 8)
void pel_main(const float4* __restrict__ P4r, const float4* __restrict__ P4p,
              float* __restrict__ acc_ws, unsigned* __restrict__ bcnt,
              float* __restrict__ out)
{
    __shared__ unsigned s_key[CAP][BLOCK];   // 21.5 KB; col-major: 2-way-free writes
    __shared__ unsigned s_tau[QPB];
    __shared__ float s_part[BLOCK / 64];

    const int t  = threadIdx.x;
    const int lq = t & (QPB - 1);
    const int sp = t >> 4;                  // split 0..15
    const int q  = blockIdx.x * QPB + lq;
    const int b  = q >> 13;
    const int i  = q & (NPTS - 1);

    const float4* __restrict__ Pq = P4r + b * NPTS;
    const float4* __restrict__ Pp = P4p + b * NPTS;

    const float4 self = Pq[i];              // (-2xi,-2yi,-2zi,sqi)
    const float xi = -0.5f * self.x, yi = -0.5f * self.y, zi = -0.5f * self.z;
    const float sqi = self.w;
    const unsigned base = (unsigned)(sp * RANGE);
    const float4* __restrict__ Pb = Pq + base;

    // ---- Phase A: branchless top-AL keys over SAMPLE prefix ----
    unsigned al[AL];
    #pragma unroll
    for (int k = 0; k < AL; ++k) al[k] = 0xFFFFFFFFu;
    for (int j0 = 0; j0 < SAMPLE; j0 += CHUNK) {
        float4 c[CHUNK];
        #pragma unroll
        for (int u = 0; u < CHUNK; ++u) c[u] = Pb[j0 + u];
        #pragma unroll
        for (int u = 0; u < CHUNK; ++u) {
            const unsigned key = mkkey(c[u], xi, yi, zi, sqi, base + j0 + u);
            #pragma unroll
            for (int k = AL - 1; k >= 1; --k) al[k] = min(al[k], max(al[k - 1], key));
            al[0] = min(al[0], key);
        }
    }
    #pragma unroll
    for (int k = 0; k < AL; ++k) s_key[k][t] = al[k];
    __syncthreads();
    {
        const unsigned tau0 = merge_tau<AL>(s_key, t);
        if (t < QPB) s_tau[t] = tau0;
    }
    __syncthreads();
    unsigned tauL = s_tau[lq];

    // ---- Phase B: branchless filter; unconditional LDS write + cond advance ----
    int cnt = 0;
    for (int j0 = 0; j0 < RANGE; j0 += CHUNK) {
        float4 c[CHUNK];
        #pragma unroll
        for (int u = 0; u < CHUNK; ++u) c[u] = Pb[j0 + u];
        #pragma unroll
        for (int u = 0; u < CHUNK; ++u) {
            const unsigned key = mkkey(c[u], xi, yi, zi, sqi, base + j0 + u);
            s_key[cnt][t] = key;                 // rejected keys get overwritten
            cnt += (key <= tauL) ? 1 : 0;
        }
        if (cnt > CAP - CHUNK) {                 // rare (P ~ 0.3%): exact compaction
            unsigned k17[KK];
            #pragma unroll
            for (int k = 0; k < KK; ++k) k17[k] = 0xFFFFFFFFu;
            for (int n = 0; n < cnt; ++n) ins17(k17, s_key[n][t]);
            const unsigned th = k17[KK - 1];
            int kept = 0;
            for (int n = 0; n < cnt; ++n) {
                const unsigned c2 = s_key[n][t];
                if (c2 <= th) { s_key[kept][t] = c2; ++kept; }
            }
            cnt = kept;                          // <= 17; +CHUNK-1 stays < CAP
            tauL = min(tauL, th);
        }
    }

    // ---- Phase C: per-thread sorted top-17 of survivors -> exact tau ----
    unsigned c17[KK];
    #pragma unroll
    for (int k = 0; k < KK; ++k) c17[k] = 0xFFFFFFFFu;
    for (int n = 0; n < cnt; ++n) ins17(c17, s_key[n][t]);
    __syncthreads();
    #pragma unroll
    for (int k = 0; k < KK; ++k) s_key[k][t] = c17[k];
    __syncthreads();
    {
        const unsigned tauX = merge_tau<KK>(s_key, t);
        if (t < QPB) s_tau[t] = tauX;            // exact 17th key incl self
    }
    __syncthreads();
    const unsigned tauK = s_tau[lq];

    // ---- Phase D: full-precision |dr - dp| over the exact accepted keys ----
    const float4 selfp = Pp[i];
    const float pxi = -0.5f * selfp.x, pyi = -0.5f * selfp.y, pzi = -0.5f * selfp.z;
    float accv = 0.0f;
    #pragma unroll
    for (int k = 0; k < KK; ++k) {
        if (c17[k] <= tauK) {
            const int j = (int)(c17[k] & JMASK);
            const float4 pr = Pq[j];
            const float er  = fmaf(pr.x, xi, fmaf(pr.y, yi, pr.z * zi)) + pr.w;
            const float d2r = fmaxf(er + sqi, 0.0f);
            const float4 pp = Pp[j];
            const float ep  = fmaf(pp.x, pxi, fmaf(pp.y, pyi, pp.z * pzi)) + pp.w;
            const float d2p = fmaxf(ep + selfp.w, 0.0f);
            accv += fabsf(sqrtf(d2r) - sqrtf(d2p));
        }
    }

    // ---- reduce block -> one atomic; last block finalizes ----
    #pragma unroll
    for (int o = 32; o > 0; o >>= 1) accv += __shfl_down(accv, o, 64);
    if ((t & 63) == 0) s_part[t >> 6] = accv;
    __syncthreads();
    if (t == 0) {
        float s = 0.0f;
        #pragma unroll
        for (int w = 0; w < BLOCK / 64; ++w) s += s_part[w];
        atomicAdd(acc_ws, s);
        __threadfence();
        const unsigned old = atomicAdd(bcnt, 1u);
        if (old == GRIDQ - 1) {
            __threadfence();
            const float total = atomicAdd(acc_ws, 0.0f);
            out[0] = total * (1.0f / (float)TOTAL_EDGES);
        }
    }
}

extern "C" void kernel_launch(void* const* d_in, const int* in_sizes, int n_in,
                              void* d_out, int out_size, void* d_ws, size_t ws_size,
                              hipStream_t stream) {
    const float* pref = (const float*)d_in[0];
    const float* pts  = (const float*)d_in[1];
    float*    acc  = (float*)d_ws;                    // ws[0]
    unsigned* bcnt = (unsigned*)d_ws + 1;             // ws[1]
    float4*   P4r  = (float4*)((char*)d_ws + 16);     // 512 KB
    float4*   P4p  = P4r + NQ;                        // 512 KB
    float*    out  = (float*)d_out;

    pel_pack<<<NQ / 256, 256, 0, stream>>>(pref, pts, P4r, P4p, acc, bcnt);
    pel_main<<<GRIDQ, BLOCK, 0, stream>>>(P4r, P4p, acc, bcnt, out);
}